// Round 1
// baseline (7144.667 us; speedup 1.0000x reference)
//
#include <hip/hip_runtime.h>
#include <math.h>

#define BB 48
#define LL 512
#define DD 192
#define HH 6
#define DKK 32
#define HID 768
#define ROWS (BB * LL)
#define BLD ((size_t)ROWS * DD)
#define SCALE_ATT 0.17677669529663687f  // 1/sqrt(32)

// ---------------------------------------------------------------------------
// Masked LayerNorm: out[row] = valid[row] ? LN(x+res)*g+b : (x+res)
// One wave (64 lanes) per row; D=192 -> 3 elements/lane.
// ---------------------------------------------------------------------------
__global__ __launch_bounds__(64) void mln_kernel(
    const float* __restrict__ x, const float* __restrict__ res,
    const int* __restrict__ valid, const float* __restrict__ g,
    const float* __restrict__ beta, float* __restrict__ out) {
  int row = blockIdx.x;
  int lane = threadIdx.x;
  const float* xr = x + (size_t)row * DD;
  float v0 = xr[lane], v1 = xr[lane + 64], v2 = xr[lane + 128];
  if (res != nullptr) {
    const float* rr = res + (size_t)row * DD;
    v0 += rr[lane]; v1 += rr[lane + 64]; v2 += rr[lane + 128];
  }
  float s = v0 + v1 + v2;
#pragma unroll
  for (int off = 32; off; off >>= 1) s += __shfl_xor(s, off);
  float mu = s * (1.0f / 192.0f);
  float d0 = v0 - mu, d1 = v1 - mu, d2 = v2 - mu;
  float ss = d0 * d0 + d1 * d1 + d2 * d2;
#pragma unroll
  for (int off = 32; off; off >>= 1) ss += __shfl_xor(ss, off);
  float inv = rsqrtf(ss * (1.0f / 192.0f) + 1e-5f);
  int vld = valid[row];
  float* outr = out + (size_t)row * DD;
  if (vld) {
    outr[lane]       = d0 * inv * g[lane]       + beta[lane];
    outr[lane + 64]  = d1 * inv * g[lane + 64]  + beta[lane + 64];
    outr[lane + 128] = d2 * inv * g[lane + 128] + beta[lane + 128];
  } else {
    outr[lane] = v0; outr[lane + 64] = v1; outr[lane + 128] = v2;
  }
}

// ---------------------------------------------------------------------------
// Generic fp32 tiled GEMM: C[M,N] = act(A[M,K] @ W[K,N] + bias[N])
// 16x16 tiles; all problem dims divide 16 so no edge guards.
// act: 0 = none, 1 = exact GELU (erf)
// ---------------------------------------------------------------------------
__global__ __launch_bounds__(256) void gemm_bias_kernel(
    const float* __restrict__ A, const float* __restrict__ W,
    const float* __restrict__ bias, float* __restrict__ C,
    int M, int N, int K, int act) {
  __shared__ float As[16][17];
  __shared__ float Ws[16][17];
  int tx = threadIdx.x, ty = threadIdx.y;
  int row = blockIdx.y * 16 + ty;
  int col = blockIdx.x * 16 + tx;
  float acc = 0.0f;
  for (int k0 = 0; k0 < K; k0 += 16) {
    As[ty][tx] = A[(size_t)row * K + k0 + tx];
    Ws[ty][tx] = W[(size_t)(k0 + ty) * N + col];
    __syncthreads();
#pragma unroll
    for (int t = 0; t < 16; ++t) acc += As[ty][t] * Ws[t][tx];
    __syncthreads();
  }
  acc += bias[col];
  if (act == 1) {
    // exact GELU: 0.5*x*(1+erf(x/sqrt(2)))
    acc = 0.5f * acc * (1.0f + erff(acc * 0.70710678118654752f));
  }
  C[(size_t)row * N + col] = acc;
}

// ---------------------------------------------------------------------------
// Attention: one wave per (batch, head, query-row).
// Q,K,V are [B*L, D] with head h at columns h*32..h*32+31.
// s = (valid_q && valid_k) ? dot*scale : -1e9 ; softmax ; o = p @ V
// ---------------------------------------------------------------------------
__global__ __launch_bounds__(64) void attn_kernel(
    const float* __restrict__ Q, const float* __restrict__ K,
    const float* __restrict__ V, const int* __restrict__ validq,
    const int* __restrict__ validk, float* __restrict__ out) {
  int bid = blockIdx.x;
  int q = bid % LL;
  int h = (bid / LL) % HH;
  int batch = bid / (LL * HH);
  int lane = threadIdx.x;

  __shared__ float qs[DKK];
  __shared__ float ps[LL];

  size_t qrow = (size_t)(batch * LL + q) * DD + h * DKK;
  if (lane < DKK) qs[lane] = Q[qrow + lane];
  __syncthreads();

  int vq = validq[batch * LL + q];

  float sc[8];
  float m = -1e30f;
#pragma unroll
  for (int i = 0; i < 8; ++i) {
    int k = i * 64 + lane;
    const float* kr = K + (size_t)(batch * LL + k) * DD + h * DKK;
    float dot = 0.0f;
#pragma unroll
    for (int d = 0; d < DKK; ++d) dot += qs[d] * kr[d];
    int vk = validk[batch * LL + k];
    sc[i] = (vq && vk) ? dot * SCALE_ATT : -1e9f;
    m = fmaxf(m, sc[i]);
  }
#pragma unroll
  for (int off = 32; off; off >>= 1) m = fmaxf(m, __shfl_xor(m, off));

  float sum = 0.0f;
#pragma unroll
  for (int i = 0; i < 8; ++i) {
    sc[i] = expf(sc[i] - m);
    sum += sc[i];
  }
#pragma unroll
  for (int off = 32; off; off >>= 1) sum += __shfl_xor(sum, off);
  float inv = 1.0f / sum;

#pragma unroll
  for (int i = 0; i < 8; ++i) ps[i * 64 + lane] = sc[i] * inv;
  __syncthreads();

  // PV: lanes 0..31 do d=lane over keys 0..255; lanes 32..63 do d=lane-32
  // over keys 256..511; combine with shfl_xor(32).
  int d = lane & 31;
  int k0 = (lane >> 5) * 256;
  float acc = 0.0f;
  for (int kk = 0; kk < 256; ++kk) {
    int k = k0 + kk;
    acc += ps[k] * V[(size_t)(batch * LL + k) * DD + h * DKK + d];
  }
  acc += __shfl_xor(acc, 32);
  if (lane < 32) out[qrow + lane] = acc;
}

// ---------------------------------------------------------------------------
extern "C" void kernel_launch(void* const* d_in, const int* in_sizes, int n_in,
                              void* d_out, int out_size, void* d_ws, size_t ws_size,
                              hipStream_t stream) {
  const float* x_a = (const float*)d_in[0];
  const float* x_b = (const float*)d_in[1];
  const int* valid_a = (const int*)d_in[2];
  const int* valid_b = (const int*)d_in[3];
  const float* ln_a_g = (const float*)d_in[4];
  const float* ln_a_b = (const float*)d_in[5];
  const float* ln_b_g = (const float*)d_in[6];
  const float* ln_b_b = (const float*)d_in[7];
  const float* ln_oa_g = (const float*)d_in[8];
  const float* ln_oa_b = (const float*)d_in[9];
  const float* ln_ob_g = (const float*)d_in[10];
  const float* ln_ob_b = (const float*)d_in[11];
  const float* wq = (const float*)d_in[12];
  const float* bq = (const float*)d_in[13];
  const float* wk = (const float*)d_in[14];
  const float* bk = (const float*)d_in[15];
  const float* wv = (const float*)d_in[16];
  const float* bv = (const float*)d_in[17];
  const float* wo = (const float*)d_in[18];
  const float* bo = (const float*)d_in[19];
  const float* fln_g = (const float*)d_in[20];
  const float* fln_b = (const float*)d_in[21];
  const float* flno_g = (const float*)d_in[22];
  const float* flno_b = (const float*)d_in[23];
  const float* w1 = (const float*)d_in[24];
  const float* b1 = (const float*)d_in[25];
  const float* w2 = (const float*)d_in[26];
  const float* b2 = (const float*)d_in[27];

  float* ws = (float*)d_ws;
  float* bufA    = ws + 0 * BLD;   // ln(x_a); later: FFN normalized input
  float* bufB    = ws + 1 * BLD;   // ln(x_b); later: FFN y
  float* bufQ    = ws + 2 * BLD;
  float* bufK    = ws + 3 * BLD;
  float* bufV    = ws + 4 * BLD;
  float* bufAttn = ws + 5 * BLD;
  float* bufTmp  = ws + 6 * BLD;
  float* bufH    = ws + 2 * BLD;   // reuses Q..Attn (4*BLD = ROWS*HID) after attn

  float* out_a = (float*)d_out;
  float* out_b = (float*)d_out + BLD;

  dim3 blk2(16, 16);
  dim3 grdD(DD / 16, ROWS / 16);    // N=192
  dim3 grdH(HID / 16, ROWS / 16);   // N=768
  int attnBlocks = BB * HH * LL;

  // --- pre-LN ---
  hipLaunchKernelGGL(mln_kernel, dim3(ROWS), dim3(64), 0, stream,
                     x_a, nullptr, valid_a, ln_a_g, ln_a_b, bufA);
  hipLaunchKernelGGL(mln_kernel, dim3(ROWS), dim3(64), 0, stream,
                     x_b, nullptr, valid_b, ln_b_g, ln_b_b, bufB);

  // --- side A: queries from a, keys/values from b ---
  hipLaunchKernelGGL(gemm_bias_kernel, grdD, blk2, 0, stream,
                     bufA, wq, bq, bufQ, ROWS, DD, DD, 0);
  hipLaunchKernelGGL(gemm_bias_kernel, grdD, blk2, 0, stream,
                     bufB, wk, bk, bufK, ROWS, DD, DD, 0);
  hipLaunchKernelGGL(gemm_bias_kernel, grdD, blk2, 0, stream,
                     bufB, wv, bv, bufV, ROWS, DD, DD, 0);
  hipLaunchKernelGGL(attn_kernel, dim3(attnBlocks), dim3(64), 0, stream,
                     bufQ, bufK, bufV, valid_a, valid_b, bufAttn);
  hipLaunchKernelGGL(gemm_bias_kernel, grdD, blk2, 0, stream,
                     bufAttn, wo, bo, bufTmp, ROWS, DD, DD, 0);
  hipLaunchKernelGGL(mln_kernel, dim3(ROWS), dim3(64), 0, stream,
                     bufTmp, x_a, valid_a, ln_oa_g, ln_oa_b, out_a);

  // --- side B: queries from b, keys/values from a ---
  hipLaunchKernelGGL(gemm_bias_kernel, grdD, blk2, 0, stream,
                     bufB, wq, bq, bufQ, ROWS, DD, DD, 0);
  hipLaunchKernelGGL(gemm_bias_kernel, grdD, blk2, 0, stream,
                     bufA, wk, bk, bufK, ROWS, DD, DD, 0);
  hipLaunchKernelGGL(gemm_bias_kernel, grdD, blk2, 0, stream,
                     bufA, wv, bv, bufV, ROWS, DD, DD, 0);
  hipLaunchKernelGGL(attn_kernel, dim3(attnBlocks), dim3(64), 0, stream,
                     bufQ, bufK, bufV, valid_b, valid_a, bufAttn);
  hipLaunchKernelGGL(gemm_bias_kernel, grdD, blk2, 0, stream,
                     bufAttn, wo, bo, bufTmp, ROWS, DD, DD, 0);
  hipLaunchKernelGGL(mln_kernel, dim3(ROWS), dim3(64), 0, stream,
                     bufTmp, x_b, valid_b, ln_ob_g, ln_ob_b, out_b);

  // --- FFN side A (bufQ..bufAttn now free -> bufH) ---
  hipLaunchKernelGGL(mln_kernel, dim3(ROWS), dim3(64), 0, stream,
                     out_a, nullptr, valid_a, fln_g, fln_b, bufA);
  hipLaunchKernelGGL(gemm_bias_kernel, grdH, blk2, 0, stream,
                     bufA, w1, b1, bufH, ROWS, HID, DD, 1);
  hipLaunchKernelGGL(gemm_bias_kernel, grdD, blk2, 0, stream,
                     bufH, w2, b2, bufB, ROWS, DD, HID, 0);
  hipLaunchKernelGGL(mln_kernel, dim3(ROWS), dim3(64), 0, stream,
                     out_a, bufB, valid_a, flno_g, flno_b, out_a);

  // --- FFN side B ---
  hipLaunchKernelGGL(mln_kernel, dim3(ROWS), dim3(64), 0, stream,
                     out_b, nullptr, valid_b, fln_g, fln_b, bufA);
  hipLaunchKernelGGL(gemm_bias_kernel, grdH, blk2, 0, stream,
                     bufA, w1, b1, bufH, ROWS, HID, DD, 1);
  hipLaunchKernelGGL(gemm_bias_kernel, grdD, blk2, 0, stream,
                     bufH, w2, b2, bufB, ROWS, DD, HID, 0);
  hipLaunchKernelGGL(mln_kernel, dim3(ROWS), dim3(64), 0, stream,
                     out_b, bufB, valid_b, flno_g, flno_b, out_b);
}

// Round 2
// 1341.040 us; speedup vs baseline: 5.3277x; 5.3277x over previous
//
#include <hip/hip_runtime.h>
#include <math.h>

#define BB 48
#define LL 512
#define DD 192
#define HH 6
#define DKK 32
#define HID 768
#define ROWS (BB * LL)
#define BLD ((size_t)ROWS * DD)
#define SCALE_ATT 0.17677669529663687f  // 1/sqrt(32)
#define CHUNK 64

// ---------------------------------------------------------------------------
// Masked LayerNorm: out[row] = valid[row] ? LN(x+res)*g+b : (x+res)
// One wave (64 lanes) per row; D=192 -> 3 elements/lane.
// ---------------------------------------------------------------------------
__global__ __launch_bounds__(64) void mln_kernel(
    const float* __restrict__ x, const float* __restrict__ res,
    const int* __restrict__ valid, const float* __restrict__ g,
    const float* __restrict__ beta, float* __restrict__ out) {
  int row = blockIdx.x;
  int lane = threadIdx.x;
  const float* xr = x + (size_t)row * DD;
  float v0 = xr[lane], v1 = xr[lane + 64], v2 = xr[lane + 128];
  if (res != nullptr) {
    const float* rr = res + (size_t)row * DD;
    v0 += rr[lane]; v1 += rr[lane + 64]; v2 += rr[lane + 128];
  }
  float s = v0 + v1 + v2;
#pragma unroll
  for (int off = 32; off; off >>= 1) s += __shfl_xor(s, off);
  float mu = s * (1.0f / 192.0f);
  float d0 = v0 - mu, d1 = v1 - mu, d2 = v2 - mu;
  float ss = d0 * d0 + d1 * d1 + d2 * d2;
#pragma unroll
  for (int off = 32; off; off >>= 1) ss += __shfl_xor(ss, off);
  float inv = rsqrtf(ss * (1.0f / 192.0f) + 1e-5f);
  int vld = valid[row];
  float* outr = out + (size_t)row * DD;
  if (vld) {
    outr[lane]       = d0 * inv * g[lane]       + beta[lane];
    outr[lane + 64]  = d1 * inv * g[lane + 64]  + beta[lane + 64];
    outr[lane + 128] = d2 * inv * g[lane + 128] + beta[lane + 128];
  } else {
    outr[lane] = v0; outr[lane + 64] = v1; outr[lane + 128] = v2;
  }
}

// ---------------------------------------------------------------------------
// Register-blocked fp32 GEMM: C[M,N] = act(A[M,K] @ W[K,N] + bias[N])
// 64x64 tile per 256-thread block, 4x4 micro-tile per thread, BK=16.
// As stored [k][m] (transposed) so compute reads are contiguous float4.
// act: 0 = none, 1 = exact GELU (erf)
// ---------------------------------------------------------------------------
__global__ __launch_bounds__(256) void gemm_rb_kernel(
    const float* __restrict__ A, const float* __restrict__ W,
    const float* __restrict__ bias, float* __restrict__ C,
    int M, int N, int K, int act) {
  __shared__ float As[16][68];  // [k][m], pad 68 keeps float4 alignment
  __shared__ float Ws[16][68];  // [k][n]
  int tid = threadIdx.x;
  int tx = tid & 15;        // n-block 0..15
  int ty = tid >> 4;        // m-block 0..15
  int row0 = blockIdx.y * 64;
  int col0 = blockIdx.x * 64;

  // load indices
  int lm = tid >> 2;              // 0..63  (A row within tile)
  int lk = (tid & 3) * 4;         // 0,4,8,12 (k float4 within row)
  int wk = tid >> 4;              // 0..15  (W row within tile)
  int wn = (tid & 15) * 4;        // 0..60  (n float4 within row)

  float acc[4][4];
#pragma unroll
  for (int i = 0; i < 4; ++i)
#pragma unroll
    for (int j = 0; j < 4; ++j) acc[i][j] = 0.0f;

  for (int k0 = 0; k0 < K; k0 += 16) {
    float4 av = *(const float4*)(A + (size_t)(row0 + lm) * K + k0 + lk);
    float4 wv = *(const float4*)(W + (size_t)(k0 + wk) * N + col0 + wn);
    __syncthreads();
    As[lk + 0][lm] = av.x;
    As[lk + 1][lm] = av.y;
    As[lk + 2][lm] = av.z;
    As[lk + 3][lm] = av.w;
    *(float4*)(&Ws[wk][wn]) = wv;
    __syncthreads();
#pragma unroll
    for (int t = 0; t < 16; ++t) {
      float4 a4 = *(const float4*)(&As[t][ty * 4]);
      float4 w4 = *(const float4*)(&Ws[t][tx * 4]);
      float ar[4] = {a4.x, a4.y, a4.z, a4.w};
      float wr[4] = {w4.x, w4.y, w4.z, w4.w};
#pragma unroll
      for (int i = 0; i < 4; ++i)
#pragma unroll
        for (int j = 0; j < 4; ++j) acc[i][j] += ar[i] * wr[j];
    }
  }

  float4 b4 = *(const float4*)(bias + col0 + tx * 4);
  float bb[4] = {b4.x, b4.y, b4.z, b4.w};
#pragma unroll
  for (int i = 0; i < 4; ++i) {
    float4 r;
    float v[4];
#pragma unroll
    for (int j = 0; j < 4; ++j) {
      float x = acc[i][j] + bb[j];
      if (act == 1) x = 0.5f * x * (1.0f + erff(x * 0.70710678118654752f));
      v[j] = x;
    }
    r.x = v[0]; r.y = v[1]; r.z = v[2]; r.w = v[3];
    *(float4*)(C + (size_t)(row0 + ty * 4 + i) * N + col0 + tx * 4) = r;
  }
}

// ---------------------------------------------------------------------------
// Flash-style attention: one THREAD per query; workgroup = 256 threads =
// 256 queries of one (batch, head). K/V staged in LDS in 64-key chunks
// (coalesced float4 loads); compute reads are same-address broadcasts.
// Online softmax (m, l) per thread. Handles fully-masked rows exactly like
// the reference (uniform 1/512 probabilities).
// ---------------------------------------------------------------------------
__global__ __launch_bounds__(256) void attn_flash_kernel(
    const float* __restrict__ Q, const float* __restrict__ K,
    const float* __restrict__ V, const int* __restrict__ validq,
    const int* __restrict__ validk, float* __restrict__ out) {
  int wg = blockIdx.x;
  int qhalf = wg & 1;
  int h = (wg >> 1) % HH;
  int batch = wg / (2 * HH);
  int tid = threadIdx.x;
  int q = qhalf * 256 + tid;

  __shared__ float Ks[CHUNK][DKK];
  __shared__ float Vs[CHUNK][DKK];
  __shared__ int vks[CHUNK];

  size_t qoff = (size_t)(batch * LL + q) * DD + h * DKK;
  float qr[DKK];
#pragma unroll
  for (int i = 0; i < 8; ++i) {
    float4 t = *(const float4*)(Q + qoff + i * 4);
    qr[i * 4 + 0] = t.x; qr[i * 4 + 1] = t.y;
    qr[i * 4 + 2] = t.z; qr[i * 4 + 3] = t.w;
  }
  int vq = validq[batch * LL + q];

  float m = -1e30f, l = 0.0f;
  float o[DKK];
#pragma unroll
  for (int d = 0; d < DKK; ++d) o[d] = 0.0f;

  for (int c = 0; c < LL; c += CHUNK) {
    __syncthreads();
    // 64 keys * 32 dims = 2048 floats = 512 float4; 2 per thread, coalesced.
#pragma unroll
    for (int i = 0; i < 2; ++i) {
      int idx = tid + i * 256;
      int kk = idx >> 3;            // key row within chunk
      int dd = (idx & 7) * 4;       // dim float4
      size_t goff = (size_t)(batch * LL + c + kk) * DD + h * DKK + dd;
      *(float4*)(&Ks[kk][dd]) = *(const float4*)(K + goff);
      *(float4*)(&Vs[kk][dd]) = *(const float4*)(V + goff);
    }
    if (tid < CHUNK) vks[tid] = validk[batch * LL + c + tid];
    __syncthreads();

    for (int kk = 0; kk < CHUNK; ++kk) {
      float dot = 0.0f;
#pragma unroll
      for (int d = 0; d < DKK; ++d) dot += qr[d] * Ks[kk][d];
      float s = (vq && vks[kk]) ? dot * SCALE_ATT : -1e9f;
      if (s > m) {
        float alpha = __expf(m - s);
        l *= alpha;
#pragma unroll
        for (int d = 0; d < DKK; ++d) o[d] *= alpha;
        m = s;
      }
      float p = __expf(s - m);
      l += p;
#pragma unroll
      for (int d = 0; d < DKK; ++d) o[d] += p * Vs[kk][d];
    }
  }
  float invl = 1.0f / l;
#pragma unroll
  for (int i = 0; i < 8; ++i) {
    float4 t;
    t.x = o[i * 4 + 0] * invl; t.y = o[i * 4 + 1] * invl;
    t.z = o[i * 4 + 2] * invl; t.w = o[i * 4 + 3] * invl;
    *(float4*)(out + qoff + i * 4) = t;
  }
}

// ---------------------------------------------------------------------------
extern "C" void kernel_launch(void* const* d_in, const int* in_sizes, int n_in,
                              void* d_out, int out_size, void* d_ws, size_t ws_size,
                              hipStream_t stream) {
  const float* x_a = (const float*)d_in[0];
  const float* x_b = (const float*)d_in[1];
  const int* valid_a = (const int*)d_in[2];
  const int* valid_b = (const int*)d_in[3];
  const float* ln_a_g = (const float*)d_in[4];
  const float* ln_a_b = (const float*)d_in[5];
  const float* ln_b_g = (const float*)d_in[6];
  const float* ln_b_b = (const float*)d_in[7];
  const float* ln_oa_g = (const float*)d_in[8];
  const float* ln_oa_b = (const float*)d_in[9];
  const float* ln_ob_g = (const float*)d_in[10];
  const float* ln_ob_b = (const float*)d_in[11];
  const float* wq = (const float*)d_in[12];
  const float* bq = (const float*)d_in[13];
  const float* wk = (const float*)d_in[14];
  const float* bk = (const float*)d_in[15];
  const float* wv = (const float*)d_in[16];
  const float* bv = (const float*)d_in[17];
  const float* wo = (const float*)d_in[18];
  const float* bo = (const float*)d_in[19];
  const float* fln_g = (const float*)d_in[20];
  const float* fln_b = (const float*)d_in[21];
  const float* flno_g = (const float*)d_in[22];
  const float* flno_b = (const float*)d_in[23];
  const float* w1 = (const float*)d_in[24];
  const float* b1 = (const float*)d_in[25];
  const float* w2 = (const float*)d_in[26];
  const float* b2 = (const float*)d_in[27];

  float* ws = (float*)d_ws;
  float* bufA    = ws + 0 * BLD;
  float* bufB    = ws + 1 * BLD;
  float* bufQ    = ws + 2 * BLD;
  float* bufK    = ws + 3 * BLD;
  float* bufV    = ws + 4 * BLD;
  float* bufAttn = ws + 5 * BLD;
  float* bufTmp  = ws + 6 * BLD;
  float* bufH    = ws + 2 * BLD;   // reuses Q..Attn (4*BLD = ROWS*HID)

  float* out_a = (float*)d_out;
  float* out_b = (float*)d_out + BLD;

  dim3 blk(256);
  dim3 grdD(DD / 64, ROWS / 64);    // N=192 -> (3, 384)
  dim3 grdH(HID / 64, ROWS / 64);   // N=768 -> (12, 384)
  int attnBlocks = BB * HH * 2;     // 576 wgs x 256 threads

  // --- pre-LN ---
  hipLaunchKernelGGL(mln_kernel, dim3(ROWS), dim3(64), 0, stream,
                     x_a, nullptr, valid_a, ln_a_g, ln_a_b, bufA);
  hipLaunchKernelGGL(mln_kernel, dim3(ROWS), dim3(64), 0, stream,
                     x_b, nullptr, valid_b, ln_b_g, ln_b_b, bufB);

  // --- side A: queries from a, keys/values from b ---
  hipLaunchKernelGGL(gemm_rb_kernel, grdD, blk, 0, stream,
                     bufA, wq, bq, bufQ, ROWS, DD, DD, 0);
  hipLaunchKernelGGL(gemm_rb_kernel, grdD, blk, 0, stream,
                     bufB, wk, bk, bufK, ROWS, DD, DD, 0);
  hipLaunchKernelGGL(gemm_rb_kernel, grdD, blk, 0, stream,
                     bufB, wv, bv, bufV, ROWS, DD, DD, 0);
  hipLaunchKernelGGL(attn_flash_kernel, dim3(attnBlocks), blk, 0, stream,
                     bufQ, bufK, bufV, valid_a, valid_b, bufAttn);
  hipLaunchKernelGGL(gemm_rb_kernel, grdD, blk, 0, stream,
                     bufAttn, wo, bo, bufTmp, ROWS, DD, DD, 0);
  hipLaunchKernelGGL(mln_kernel, dim3(ROWS), dim3(64), 0, stream,
                     bufTmp, x_a, valid_a, ln_oa_g, ln_oa_b, out_a);

  // --- side B: queries from b, keys/values from a ---
  hipLaunchKernelGGL(gemm_rb_kernel, grdD, blk, 0, stream,
                     bufB, wq, bq, bufQ, ROWS, DD, DD, 0);
  hipLaunchKernelGGL(gemm_rb_kernel, grdD, blk, 0, stream,
                     bufA, wk, bk, bufK, ROWS, DD, DD, 0);
  hipLaunchKernelGGL(gemm_rb_kernel, grdD, blk, 0, stream,
                     bufA, wv, bv, bufV, ROWS, DD, DD, 0);
  hipLaunchKernelGGL(attn_flash_kernel, dim3(attnBlocks), blk, 0, stream,
                     bufQ, bufK, bufV, valid_b, valid_a, bufAttn);
  hipLaunchKernelGGL(gemm_rb_kernel, grdD, blk, 0, stream,
                     bufAttn, wo, bo, bufTmp, ROWS, DD, DD, 0);
  hipLaunchKernelGGL(mln_kernel, dim3(ROWS), dim3(64), 0, stream,
                     bufTmp, x_b, valid_b, ln_ob_g, ln_ob_b, out_b);

  // --- FFN side A (bufQ..bufAttn now free -> bufH) ---
  hipLaunchKernelGGL(mln_kernel, dim3(ROWS), dim3(64), 0, stream,
                     out_a, nullptr, valid_a, fln_g, fln_b, bufA);
  hipLaunchKernelGGL(gemm_rb_kernel, grdH, blk, 0, stream,
                     bufA, w1, b1, bufH, ROWS, HID, DD, 1);
  hipLaunchKernelGGL(gemm_rb_kernel, grdD, blk, 0, stream,
                     bufH, w2, b2, bufB, ROWS, DD, HID, 0);
  hipLaunchKernelGGL(mln_kernel, dim3(ROWS), dim3(64), 0, stream,
                     out_a, bufB, valid_a, flno_g, flno_b, out_a);

  // --- FFN side B ---
  hipLaunchKernelGGL(mln_kernel, dim3(ROWS), dim3(64), 0, stream,
                     out_b, nullptr, valid_b, fln_g, fln_b, bufA);
  hipLaunchKernelGGL(gemm_rb_kernel, grdH, blk, 0, stream,
                     bufA, w1, b1, bufH, ROWS, HID, DD, 1);
  hipLaunchKernelGGL(gemm_rb_kernel, grdD, blk, 0, stream,
                     bufH, w2, b2, bufB, ROWS, DD, HID, 0);
  hipLaunchKernelGGL(mln_kernel, dim3(ROWS), dim3(64), 0, stream,
                     out_b, bufB, valid_b, flno_g, flno_b, out_b);
}